// Round 1
// baseline (55.733 us; speedup 1.0000x reference)
//
#include <hip/hip_runtime.h>

// DynamicMaskHead: per-instance dynamic MLP over mask feats + 4x aligned bilinear + sigmoid.
// Shapes fixed by harness setup_inputs(): N=2, Cin=8, H=100, W=152, n_inst=100, stride=8.

#define CIN 8
#define HH 100
#define WW 152
#define HWSZ (HH * WW)
#define NI 100
#define FACTOR 4
#define OH (HH * FACTOR)
#define OW (WW * FACTOR)

__device__ __forceinline__ float fast_mish(float x) {
    // mish(x) = x * tanh(softplus(x)) = x * e(e+2)/(e(e+2)+2), e = exp(x)
    if (x > 30.f) return x;                 // tanh(softplus(30)) == 1 to fp32
    float e = __expf(x);
    float n = e * (e + 2.f);
    return x * n / (n + 2.f);
}

__global__ void mask_head_mlp_kernel(const float* __restrict__ mask_feats,
                                     const float* __restrict__ params,
                                     const float* __restrict__ inst_locs,
                                     const int* __restrict__ im_inds,
                                     const int* __restrict__ fpn_levels,
                                     const int* __restrict__ stride_ptr,
                                     float* __restrict__ logits) {
    __shared__ float prm[169];
    const int inst = blockIdx.y;
    // stage this instance's params in LDS
    for (int t = threadIdx.x; t < 169; t += blockDim.x)
        prm[t] = params[inst * 169 + t];
    __syncthreads();

    const int p = blockIdx.x * blockDim.x + threadIdx.x;
    if (p >= HWSZ) return;

    const int stride = stride_ptr[0];
    const float half = (float)(stride / 2);
    const int py = p / WW;
    const int px = p - py * WW;

    const float soi_tab[5] = {64.f, 128.f, 256.f, 512.f, 1024.f};
    const float inv_soi = 1.f / soi_tab[fpn_levels[inst]];   // powers of 2: exact
    const float lx = inst_locs[inst * 2 + 0];
    const float ly = inst_locs[inst * 2 + 1];

    float xin[10];
    xin[0] = (lx - (float)(px * stride) - half) * inv_soi;
    xin[1] = (ly - (float)(py * stride) - half) * inv_soi;

    const float* fb = mask_feats + (size_t)im_inds[inst] * CIN * HWSZ + p;
#pragma unroll
    for (int c = 0; c < CIN; ++c) xin[2 + c] = fb[(size_t)c * HWSZ];

    // layer 1: 10 -> 8, mish   (w1 at [0,80) row-major [8][10], b1 at [152,160))
    float h1[8];
#pragma unroll
    for (int o = 0; o < 8; ++o) {
        float acc = prm[152 + o];
#pragma unroll
        for (int i = 0; i < 10; ++i) acc = fmaf(prm[o * 10 + i], xin[i], acc);
        h1[o] = fast_mish(acc);
    }
    // layer 2: 8 -> 8, mish    (w2 at [80,144) [8][8], b2 at [160,168))
    float h2[8];
#pragma unroll
    for (int o = 0; o < 8; ++o) {
        float acc = prm[160 + o];
#pragma unroll
        for (int i = 0; i < 8; ++i) acc = fmaf(prm[80 + o * 8 + i], h1[i], acc);
        h2[o] = fast_mish(acc);
    }
    // layer 3: 8 -> 1          (w3 at [144,152), b3 at 168)
    float acc = prm[168];
#pragma unroll
    for (int i = 0; i < 8; ++i) acc = fmaf(prm[144 + i], h2[i], acc);

    logits[(size_t)inst * HWSZ + p] = acc;
}

// aligned_bilinear(factor=4) + sigmoid. Each thread produces 4 consecutive X
// outputs -> float4 store. Padded size (H+1, W+1) with edge replication;
// coords = max(out - 2, 0)/4; i1 clamped to padded end -> row/col clamp to H-1/W-1.
__global__ void upsample_sigmoid_kernel(const float* __restrict__ logits,
                                        float* __restrict__ out) {
    const int gpr = OW / 4;                  // groups per row = 152
    const int per_inst = OH * gpr;           // 60800
    const int idx = blockIdx.x * blockDim.x + threadIdx.x;
    if (idx >= NI * per_inst) return;

    const int inst = idx / per_inst;
    int rem = idx - inst * per_inst;
    const int Y = rem / gpr;
    const int g = rem - Y * gpr;

    const float* L = logits + (size_t)inst * HWSZ;

    const float yc = (float)max(Y - 2, 0) * 0.25f;
    const int y0 = (int)yc;
    const float fy = yc - (float)y0;
    const int r0 = min(y0, HH - 1);
    const int r1 = min(y0 + 1, HH - 1);
    const float* row0 = L + r0 * WW;
    const float* row1 = L + r1 * WW;

    float v[4];
#pragma unroll
    for (int k = 0; k < 4; ++k) {
        const int X = 4 * g + k;
        const float xc = (float)max(X - 2, 0) * 0.25f;
        const int x0 = (int)xc;
        const float fx = xc - (float)x0;
        const int c0 = min(x0, WW - 1);
        const int c1 = min(x0 + 1, WW - 1);
        const float a0 = row0[c0], a1 = row0[c1];
        const float b0 = row1[c0], b1 = row1[c1];
        const float top = a0 + fx * (a1 - a0);
        const float bot = b0 + fx * (b1 - b0);
        const float z = top + fy * (bot - top);
        v[k] = 1.f / (1.f + __expf(-z));
    }
    float4 res = make_float4(v[0], v[1], v[2], v[3]);
    *reinterpret_cast<float4*>(out + (size_t)inst * (OH * OW) + (size_t)Y * OW + 4 * g) = res;
}

extern "C" void kernel_launch(void* const* d_in, const int* in_sizes, int n_in,
                              void* d_out, int out_size, void* d_ws, size_t ws_size,
                              hipStream_t stream) {
    const float* mask_feats = (const float*)d_in[0];
    const float* params     = (const float*)d_in[1];
    const float* inst_locs  = (const float*)d_in[2];
    const int*   im_inds    = (const int*)d_in[3];
    const int*   fpn_levels = (const int*)d_in[4];
    const int*   stride_ptr = (const int*)d_in[5];
    float* out    = (float*)d_out;
    float* logits = (float*)d_ws;            // NI*HWSZ floats = 6.08 MB

    dim3 block(256);
    dim3 grid1((HWSZ + 255) / 256, NI);
    mask_head_mlp_kernel<<<grid1, block, 0, stream>>>(
        mask_feats, params, inst_locs, im_inds, fpn_levels, stride_ptr, logits);

    const int total_g = NI * OH * (OW / 4);  // 6,080,000
    dim3 grid2((total_g + 255) / 256);
    upsample_sigmoid_kernel<<<grid2, block, 0, stream>>>(logits, out);
}

// Round 3
// 40.049 us; speedup vs baseline: 1.3916x; 1.3916x over previous
//
#include <hip/hip_runtime.h>

// DynamicMaskHead: per-instance dynamic MLP over mask feats + 4x aligned bilinear + sigmoid.
// Shapes fixed by harness setup_inputs(): N=2, Cin=8, H=100, W=152, n_inst=100, stride=8.

#define CIN 8
#define HH 100
#define WW 152
#define HWSZ (HH * WW)
#define NI 100
#define FACTOR 4
#define OH (HH * FACTOR)
#define OW (WW * FACTOR)

__device__ __forceinline__ float fast_rcp(float x) {
    return __builtin_amdgcn_rcpf(x);       // v_rcp_f32, ~1 ulp
}

__device__ __forceinline__ float fast_mish(float x) {
    // mish(x) = x * tanh(softplus(x)) = x * n/(n+2), n = e(e+2), e = exp(x)
    if (x > 30.f) return x;                 // tanh(softplus(30)) == 1 to fp32
    float e = __expf(x);
    float n = e * (e + 2.f);
    return x * n * fast_rcp(n + 2.f);
}

__device__ __forceinline__ float fast_sigmoid(float z) {
    return fast_rcp(1.f + __expf(-z));
}

__global__ void mask_head_mlp_kernel(const float* __restrict__ mask_feats,
                                     const float* __restrict__ params,
                                     const float* __restrict__ inst_locs,
                                     const int* __restrict__ im_inds,
                                     const int* __restrict__ fpn_levels,
                                     const int* __restrict__ stride_ptr,
                                     float* __restrict__ logits) {
    __shared__ float prm[169];
    const int inst = blockIdx.y;
    for (int t = threadIdx.x; t < 169; t += blockDim.x)
        prm[t] = params[inst * 169 + t];
    __syncthreads();

    const int p = blockIdx.x * blockDim.x + threadIdx.x;
    if (p >= HWSZ) return;

    const int stride = stride_ptr[0];
    const float half = (float)(stride / 2);
    const int py = p / WW;
    const int px = p - py * WW;

    const float soi_tab[5] = {64.f, 128.f, 256.f, 512.f, 1024.f};
    const float inv_soi = 1.f / soi_tab[fpn_levels[inst]];   // powers of 2: exact
    const float lx = inst_locs[inst * 2 + 0];
    const float ly = inst_locs[inst * 2 + 1];

    float xin[10];
    xin[0] = (lx - (float)(px * stride) - half) * inv_soi;
    xin[1] = (ly - (float)(py * stride) - half) * inv_soi;

    const float* fb = mask_feats + (size_t)im_inds[inst] * CIN * HWSZ + p;
#pragma unroll
    for (int c = 0; c < CIN; ++c) xin[2 + c] = fb[(size_t)c * HWSZ];

    // layer 1: 10 -> 8, mish   (w1 at [0,80) row-major [8][10], b1 at [152,160))
    float h1[8];
#pragma unroll
    for (int o = 0; o < 8; ++o) {
        float acc = prm[152 + o];
#pragma unroll
        for (int i = 0; i < 10; ++i) acc = fmaf(prm[o * 10 + i], xin[i], acc);
        h1[o] = fast_mish(acc);
    }
    // layer 2: 8 -> 8, mish    (w2 at [80,144) [8][8], b2 at [160,168))
    float h2[8];
#pragma unroll
    for (int o = 0; o < 8; ++o) {
        float acc = prm[160 + o];
#pragma unroll
        for (int i = 0; i < 8; ++i) acc = fmaf(prm[80 + o * 8 + i], h1[i], acc);
        h2[o] = fast_mish(acc);
    }
    // layer 3: 8 -> 1          (w3 at [144,152), b3 at 168)
    float acc = prm[168];
#pragma unroll
    for (int i = 0; i < 8; ++i) acc = fmaf(prm[144 + i], h2[i], acc);

    logits[(size_t)inst * HWSZ + p] = acc;
}

// aligned_bilinear(factor=4) + sigmoid, constant-weight form.
// Output index Y=4r+k samples coord c=max(Y-2,0)/4:
//   k=0: c=r-0.5  -> 0.50*row(r-1) + 0.50*row(r)
//   k=1: c=r-0.25 -> 0.25*row(r-1) + 0.75*row(r)   (frac=0.75!)
//   k=2: c=r      -> 1.00*row(r)
//   k=3: c=r+0.25 -> 0.75*row(r)   + 0.25*row(r+1)
// (indices clamped to [0,H-1]; clamp+fixed-weight reproduces the reference's
//  edge-pad + max(Y-2,0) semantics exactly, incl. r=0 and r=H-1). Same in X.
// One thread -> 4x4 output block from a 3x3 input neighborhood.
__global__ void upsample_sigmoid_kernel(const float* __restrict__ logits,
                                        float* __restrict__ out) {
    const int per_inst = HH * WW;            // one thread per input pixel
    const int idx = blockIdx.x * blockDim.x + threadIdx.x;
    if (idx >= NI * per_inst) return;

    const int inst = idx / per_inst;
    int rem = idx - inst * per_inst;
    const int r = rem / WW;
    const int g = rem - r * WW;

    const float* L = logits + (size_t)inst * HWSZ;
    const int rm1 = max(r - 1, 0), rp1 = min(r + 1, HH - 1);
    const int gm1 = max(g - 1, 0), gp1 = min(g + 1, WW - 1);

    // 3x3 neighborhood (prev/cur/next row and col)
    float v00 = L[rm1 * WW + gm1], v01 = L[rm1 * WW + g], v02 = L[rm1 * WW + gp1];
    float v10 = L[r   * WW + gm1], v11 = L[r   * WW + g], v12 = L[r   * WW + gp1];
    float v20 = L[rp1 * WW + gm1], v21 = L[rp1 * WW + g], v22 = L[rp1 * WW + gp1];

    // horizontal interp per row: x-samples k=0..3 (prev=v*0, cur=v*1, next=v*2)
    float h0[4], h1[4], h2[4];
    h0[0] = 0.5f * (v00 + v01); h0[1] = fmaf(0.25f, v00, 0.75f * v01); h0[2] = v01; h0[3] = fmaf(0.25f, v02, 0.75f * v01);
    h1[0] = 0.5f * (v10 + v11); h1[1] = fmaf(0.25f, v10, 0.75f * v11); h1[2] = v11; h1[3] = fmaf(0.25f, v12, 0.75f * v11);
    h2[0] = 0.5f * (v20 + v21); h2[1] = fmaf(0.25f, v20, 0.75f * v21); h2[2] = v21; h2[3] = fmaf(0.25f, v22, 0.75f * v21);

    float* O = out + (size_t)inst * (OH * OW) + (size_t)(4 * r) * OW + 4 * g;

    float4 row;
    // k=0: 0.5*prev + 0.5*cur
    row.x = fast_sigmoid(0.5f * (h0[0] + h1[0]));
    row.y = fast_sigmoid(0.5f * (h0[1] + h1[1]));
    row.z = fast_sigmoid(0.5f * (h0[2] + h1[2]));
    row.w = fast_sigmoid(0.5f * (h0[3] + h1[3]));
    *reinterpret_cast<float4*>(O) = row;
    // k=1: 0.25*prev + 0.75*cur
    row.x = fast_sigmoid(fmaf(0.25f, h0[0], 0.75f * h1[0]));
    row.y = fast_sigmoid(fmaf(0.25f, h0[1], 0.75f * h1[1]));
    row.z = fast_sigmoid(fmaf(0.25f, h0[2], 0.75f * h1[2]));
    row.w = fast_sigmoid(fmaf(0.25f, h0[3], 0.75f * h1[3]));
    *reinterpret_cast<float4*>(O + OW) = row;
    // k=2: cur
    row.x = fast_sigmoid(h1[0]);
    row.y = fast_sigmoid(h1[1]);
    row.z = fast_sigmoid(h1[2]);
    row.w = fast_sigmoid(h1[3]);
    *reinterpret_cast<float4*>(O + 2 * OW) = row;
    // k=3: 0.75*cur + 0.25*next
    row.x = fast_sigmoid(fmaf(0.25f, h2[0], 0.75f * h1[0]));
    row.y = fast_sigmoid(fmaf(0.25f, h2[1], 0.75f * h1[1]));
    row.z = fast_sigmoid(fmaf(0.25f, h2[2], 0.75f * h1[2]));
    row.w = fast_sigmoid(fmaf(0.25f, h2[3], 0.75f * h1[3]));
    *reinterpret_cast<float4*>(O + 3 * OW) = row;
}

extern "C" void kernel_launch(void* const* d_in, const int* in_sizes, int n_in,
                              void* d_out, int out_size, void* d_ws, size_t ws_size,
                              hipStream_t stream) {
    const float* mask_feats = (const float*)d_in[0];
    const float* params     = (const float*)d_in[1];
    const float* inst_locs  = (const float*)d_in[2];
    const int*   im_inds    = (const int*)d_in[3];
    const int*   fpn_levels = (const int*)d_in[4];
    const int*   stride_ptr = (const int*)d_in[5];
    float* out    = (float*)d_out;
    float* logits = (float*)d_ws;            // NI*HWSZ floats = 6.08 MB

    dim3 block(256);
    dim3 grid1((HWSZ + 255) / 256, NI);
    mask_head_mlp_kernel<<<grid1, block, 0, stream>>>(
        mask_feats, params, inst_locs, im_inds, fpn_levels, stride_ptr, logits);

    const int total_t = NI * HH * WW;        // 1,520,000 threads, 4x4 out each
    dim3 grid2((total_t + 255) / 256);
    upsample_sigmoid_kernel<<<grid2, block, 0, stream>>>(logits, out);
}